// Round 3
// baseline (273.302 us; speedup 1.0000x reference)
//
#include <hip/hip_runtime.h>

#define BB 4
#define HH 512
#define WW 512
#define KK 7
#define PP 3
#define CC 256
#define RH 128                 // region height
#define RW 32                  // region width
#define SH (RH + 2 * PP)       // 134
#define SW (RW + 2 * PP)       // 38
#define NT 1024                // threads per block
#define NWAVE (NT / 64)        // 16

// Scatter active-site linear index into dense idx_map (pre-filled with -1).
__global__ void smconv_scatter(const int* __restrict__ idx,
                               int* __restrict__ idx_map, int n) {
    int i = blockIdx.x * blockDim.x + threadIdx.x;
    if (i >= n) return;
    int b = idx[i * 3 + 0];
    int y = idx[i * 3 + 1];
    int x = idx[i * 3 + 2];
    idx_map[((size_t)b * HH + y) * WW + x] = i;
}

// Transpose weight (C, K, K) -> (K*K, C) so channel-major loads coalesce.
__global__ void smconv_wt(const float* __restrict__ w, float* __restrict__ w_t) {
    int i = blockIdx.x * blockDim.x + threadIdx.x;
    if (i >= KK * KK * CC) return;
    int tap = i / CC;
    int c = i - tap * CC;
    w_t[i] = w[c * KK * KK + tap];
}

// One block per 128x32 region (256 blocks = 1/CU). 16 waves round-robin a
// scan-ordered active-site list; one wave per site, lane owns 4 channels.
// 4-deep load peel for memory-level parallelism.
__global__ void __launch_bounds__(NT)
smconv_conv_region(const float* __restrict__ feat,
                   const float* __restrict__ w_t,
                   const float* __restrict__ bias,
                   const int* __restrict__ idx_map,
                   float* __restrict__ out) {
    __shared__ int smap[SH * SW];
    __shared__ unsigned short lst[RH * RW];
    __shared__ int wcnt[NWAVE];

    const int tid  = threadIdx.x;
    const int wave = tid >> 6;
    const int lane = tid & 63;

    // XCD-chunked swizzle: XCD k owns 32 contiguous regions (a 512x256 slab).
    const int r  = (blockIdx.x & 7) * 32 + (blockIdx.x >> 3);
    const int b  = r >> 6;              // 64 regions per batch
    const int rm = r & 63;
    const int rx = rm >> 2;             // 16 column strips, column-major order
    const int ry = rm & 3;              // 4 row strips
    const int y0 = ry * RH;
    const int x0 = rx * RW;

    // Stage region+halo idx_map into LDS (-1 outside image).
    for (int i = tid; i < SH * SW; i += NT) {
        int gy = y0 + i / SW - PP;
        int gx = x0 + i % SW - PP;
        int v = -1;
        if (gy >= 0 && gy < HH && gx >= 0 && gx < WW)
            v = idx_map[((size_t)b * HH + gy) * WW + gx];
        smap[i] = v;
    }
    __syncthreads();

    // Build active-site list in deterministic scan order.
    int total = 0;
    for (int c = 0; c < RH * RW; c += NT) {
        int i = c + tid;
        int iy = i >> 5;
        int ix = i & (RW - 1);
        bool act = smap[(iy + PP) * SW + (ix + PP)] >= 0;
        unsigned long long bal = __ballot(act);
        if (lane == 0) wcnt[wave] = __popcll(bal);
        __syncthreads();
        int off = total;
        for (int w = 0; w < wave; ++w) off += wcnt[w];
        if (act)
            lst[off + __popcll(bal & ((1ull << lane) - 1))] = (unsigned short)i;
        int t2 = total;
        for (int w = 0; w < NWAVE; ++w) t2 += wcnt[w];
        total = t2;
        __syncthreads();
    }

    const int c4 = lane * 4;
    const int dy = lane / KK;   // tap row (lane < 49)
    const int dx = lane % KK;   // tap col
    const float4 bv = *(const float4*)(bias + c4);

    for (int e = wave; e < total; e += NWAVE) {
        const int pos = lst[e];
        const int iy = pos >> 5;
        const int ix = pos & (RW - 1);

        int nb = -1;
        if (lane < KK * KK)
            nb = smap[(iy + dy) * SW + (ix + dx)];

        const int site = __shfl(nb, PP * KK + PP);   // center tap = own id
        unsigned long long mask = __ballot(nb >= 0);

        float4 acc = make_float4(0.f, 0.f, 0.f, 0.f);

        while (mask) {
            // Peel up to 4 taps; dummies repeat t0 (L1-hit) and skip the fma.
            int t0 = __ffsll((long long)mask) - 1; mask &= mask - 1;
            bool h1 = mask != 0;
            int t1 = h1 ? __ffsll((long long)mask) - 1 : t0;
            if (h1) mask &= mask - 1;
            bool h2 = mask != 0;
            int t2 = h2 ? __ffsll((long long)mask) - 1 : t0;
            if (h2) mask &= mask - 1;
            bool h3 = mask != 0;
            int t3 = h3 ? __ffsll((long long)mask) - 1 : t0;
            if (h3) mask &= mask - 1;

            int n0 = __shfl(nb, t0);
            int n1 = __shfl(nb, t1);
            int n2 = __shfl(nb, t2);
            int n3 = __shfl(nb, t3);

            float4 f0 = *(const float4*)(feat + (size_t)n0 * CC + c4);
            float4 w0 = *(const float4*)(w_t + t0 * CC + c4);
            float4 f1 = *(const float4*)(feat + (size_t)n1 * CC + c4);
            float4 w1 = *(const float4*)(w_t + t1 * CC + c4);
            float4 f2 = *(const float4*)(feat + (size_t)n2 * CC + c4);
            float4 w2 = *(const float4*)(w_t + t2 * CC + c4);
            float4 f3 = *(const float4*)(feat + (size_t)n3 * CC + c4);
            float4 w3 = *(const float4*)(w_t + t3 * CC + c4);

            acc.x = fmaf(f0.x, w0.x, acc.x);
            acc.y = fmaf(f0.y, w0.y, acc.y);
            acc.z = fmaf(f0.z, w0.z, acc.z);
            acc.w = fmaf(f0.w, w0.w, acc.w);
            if (h1) {
                acc.x = fmaf(f1.x, w1.x, acc.x);
                acc.y = fmaf(f1.y, w1.y, acc.y);
                acc.z = fmaf(f1.z, w1.z, acc.z);
                acc.w = fmaf(f1.w, w1.w, acc.w);
            }
            if (h2) {
                acc.x = fmaf(f2.x, w2.x, acc.x);
                acc.y = fmaf(f2.y, w2.y, acc.y);
                acc.z = fmaf(f2.z, w2.z, acc.z);
                acc.w = fmaf(f2.w, w2.w, acc.w);
            }
            if (h3) {
                acc.x = fmaf(f3.x, w3.x, acc.x);
                acc.y = fmaf(f3.y, w3.y, acc.y);
                acc.z = fmaf(f3.z, w3.z, acc.z);
                acc.w = fmaf(f3.w, w3.w, acc.w);
            }
        }

        float4 o = make_float4(acc.x + bv.x, acc.y + bv.y,
                               acc.z + bv.z, acc.w + bv.w);
        *(float4*)(out + (size_t)site * CC + c4) = o;
    }
}

extern "C" void kernel_launch(void* const* d_in, const int* in_sizes, int n_in,
                              void* d_out, int out_size, void* d_ws, size_t ws_size,
                              hipStream_t stream) {
    const float* feat = (const float*)d_in[0];
    const int*   idx  = (const int*)d_in[1];
    const float* w    = (const float*)d_in[2];
    const float* bias = (const float*)d_in[3];
    float* out = (float*)d_out;

    const int n = in_sizes[0] / CC;  // number of active sites

    int*   idx_map = (int*)d_ws;
    float* w_t     = (float*)((char*)d_ws + (size_t)BB * HH * WW * sizeof(int));

    // 1) idx_map = -1
    hipMemsetAsync(idx_map, 0xFF, (size_t)BB * HH * WW * sizeof(int), stream);
    // 2) scatter site ids
    smconv_scatter<<<(n + 255) / 256, 256, 0, stream>>>(idx, idx_map, n);
    // 3) transpose weights to (tap, C)
    smconv_wt<<<(KK * KK * CC + 255) / 256, 256, 0, stream>>>(w, w_t);
    // 4) region conv: one block per 128x32 region, 256 blocks total
    const int nregions = BB * (HH / RH) * (WW / RW);  // 256
    smconv_conv_region<<<nregions, NT, 0, stream>>>(feat, w_t, bias, idx_map, out);
}

// Round 4
// 198.589 us; speedup vs baseline: 1.3762x; 1.3762x over previous
//
#include <hip/hip_runtime.h>

#define BB 4
#define HH 512
#define WW 512
#define KK 7
#define PP 3
#define CC 256
#define RH 64                  // region height
#define RW 32                  // region width
#define SH (RH + 2 * PP)       // 70
#define SW (RW + 2 * PP)       // 38
#define NT 1024                // threads per block
#define NWAVE (NT / 64)        // 16
#define NREG (BB * (HH / RH) * (WW / RW))   // 512

// Scatter active-site linear index into dense idx_map (pre-filled with -1).
__global__ void smconv_scatter(const int* __restrict__ idx,
                               int* __restrict__ idx_map, int n) {
    int i = blockIdx.x * blockDim.x + threadIdx.x;
    if (i >= n) return;
    int b = idx[i * 3 + 0];
    int y = idx[i * 3 + 1];
    int x = idx[i * 3 + 2];
    idx_map[((size_t)b * HH + y) * WW + x] = i;
}

// Transpose weight (C, K, K) -> (K*K, C) so channel-major loads coalesce.
__global__ void smconv_wt(const float* __restrict__ w, float* __restrict__ w_t) {
    int i = blockIdx.x * blockDim.x + threadIdx.x;
    if (i >= KK * KK * CC) return;
    int tap = i / CC;
    int c = i - tap * CC;
    w_t[i] = w[c * KK * KK + tap];
}

// One block per 64x32 region (512 blocks = 2/CU = 32 waves/CU). 16 waves
// round-robin a scan-ordered active-site list; one wave per site, lane owns
// 4 channels. Weights served from LDS (no TA/VMEM cost); 4-deep load peel.
__global__ void __launch_bounds__(NT)
smconv_conv_region(const float* __restrict__ feat,
                   const float* __restrict__ w_t,
                   const float* __restrict__ bias,
                   const int* __restrict__ idx_map,
                   float* __restrict__ out) {
    __shared__ int smap[SH * SW];                 // 10,640 B
    __shared__ unsigned short lst[RH * RW];       //  4,096 B
    __shared__ int wcnt[NWAVE];
    __shared__ float w_lds[KK * KK * CC];         // 50,176 B

    const int tid  = threadIdx.x;
    const int wave = tid >> 6;
    const int lane = tid & 63;

    // XCD-chunked swizzle: XCD k owns 64 contiguous regions (512x256 slab,
    // column-major region order so y-adjacent regions are consecutive).
    const int r  = (blockIdx.x & 7) * 64 + (blockIdx.x >> 3);
    const int b  = r >> 7;              // 128 regions per batch
    const int rm = r & 127;
    const int rx = rm >> 3;             // 16 column strips
    const int ry = rm & 7;              // 8 row strips
    const int y0 = ry * RH;
    const int x0 = rx * RW;

    // Stage weights (tap, C) into LDS, coalesced float4.
    for (int i = tid; i < KK * KK * CC / 4; i += NT)
        ((float4*)w_lds)[i] = ((const float4*)w_t)[i];

    // Stage region+halo idx_map into LDS (-1 outside image).
    for (int i = tid; i < SH * SW; i += NT) {
        int gy = y0 + i / SW - PP;
        int gx = x0 + i % SW - PP;
        int v = -1;
        if (gy >= 0 && gy < HH && gx >= 0 && gx < WW)
            v = idx_map[((size_t)b * HH + gy) * WW + gx];
        smap[i] = v;
    }
    __syncthreads();

    // Build active-site list in deterministic scan order.
    int total = 0;
    for (int c = 0; c < RH * RW; c += NT) {
        int i = c + tid;
        int iy = i >> 5;
        int ix = i & (RW - 1);
        bool act = smap[(iy + PP) * SW + (ix + PP)] >= 0;
        unsigned long long bal = __ballot(act);
        if (lane == 0) wcnt[wave] = __popcll(bal);
        __syncthreads();
        int off = total;
        for (int w = 0; w < wave; ++w) off += wcnt[w];
        if (act)
            lst[off + __popcll(bal & ((1ull << lane) - 1))] = (unsigned short)i;
        int t2 = total;
        for (int w = 0; w < NWAVE; ++w) t2 += wcnt[w];
        total = t2;
        __syncthreads();
    }

    const int c4 = lane * 4;
    const int dy = lane / KK;   // tap row (lane < 49)
    const int dx = lane % KK;   // tap col
    const float4 bv = *(const float4*)(bias + c4);

    for (int e = wave; e < total; e += NWAVE) {
        const int pos = lst[e];
        const int iy = pos >> 5;
        const int ix = pos & (RW - 1);

        int nb = -1;
        if (lane < KK * KK)
            nb = smap[(iy + dy) * SW + (ix + dx)];

        const int site = __shfl(nb, PP * KK + PP);   // center tap = own id
        unsigned long long mask = __ballot(nb >= 0);

        float4 acc = make_float4(0.f, 0.f, 0.f, 0.f);

        while (mask) {
            // Peel up to 4 taps; dummies repeat t0 and skip the fma.
            int t0 = __ffsll((long long)mask) - 1; mask &= mask - 1;
            bool h1 = mask != 0;
            int t1 = h1 ? __ffsll((long long)mask) - 1 : t0;
            if (h1) mask &= mask - 1;
            bool h2 = mask != 0;
            int t2 = h2 ? __ffsll((long long)mask) - 1 : t0;
            if (h2) mask &= mask - 1;
            bool h3 = mask != 0;
            int t3 = h3 ? __ffsll((long long)mask) - 1 : t0;
            if (h3) mask &= mask - 1;

            int n0 = __shfl(nb, t0);
            int n1 = __shfl(nb, t1);
            int n2 = __shfl(nb, t2);
            int n3 = __shfl(nb, t3);

            float4 f0 = *(const float4*)(feat + (size_t)n0 * CC + c4);
            float4 f1 = *(const float4*)(feat + (size_t)n1 * CC + c4);
            float4 f2 = *(const float4*)(feat + (size_t)n2 * CC + c4);
            float4 f3 = *(const float4*)(feat + (size_t)n3 * CC + c4);
            float4 w0 = *(const float4*)(w_lds + t0 * CC + c4);
            float4 w1 = *(const float4*)(w_lds + t1 * CC + c4);
            float4 w2 = *(const float4*)(w_lds + t2 * CC + c4);
            float4 w3 = *(const float4*)(w_lds + t3 * CC + c4);

            acc.x = fmaf(f0.x, w0.x, acc.x);
            acc.y = fmaf(f0.y, w0.y, acc.y);
            acc.z = fmaf(f0.z, w0.z, acc.z);
            acc.w = fmaf(f0.w, w0.w, acc.w);
            if (h1) {
                acc.x = fmaf(f1.x, w1.x, acc.x);
                acc.y = fmaf(f1.y, w1.y, acc.y);
                acc.z = fmaf(f1.z, w1.z, acc.z);
                acc.w = fmaf(f1.w, w1.w, acc.w);
            }
            if (h2) {
                acc.x = fmaf(f2.x, w2.x, acc.x);
                acc.y = fmaf(f2.y, w2.y, acc.y);
                acc.z = fmaf(f2.z, w2.z, acc.z);
                acc.w = fmaf(f2.w, w2.w, acc.w);
            }
            if (h3) {
                acc.x = fmaf(f3.x, w3.x, acc.x);
                acc.y = fmaf(f3.y, w3.y, acc.y);
                acc.z = fmaf(f3.z, w3.z, acc.z);
                acc.w = fmaf(f3.w, w3.w, acc.w);
            }
        }

        float4 o = make_float4(acc.x + bv.x, acc.y + bv.y,
                               acc.z + bv.z, acc.w + bv.w);
        *(float4*)(out + (size_t)site * CC + c4) = o;
    }
}

extern "C" void kernel_launch(void* const* d_in, const int* in_sizes, int n_in,
                              void* d_out, int out_size, void* d_ws, size_t ws_size,
                              hipStream_t stream) {
    const float* feat = (const float*)d_in[0];
    const int*   idx  = (const int*)d_in[1];
    const float* w    = (const float*)d_in[2];
    const float* bias = (const float*)d_in[3];
    float* out = (float*)d_out;

    const int n = in_sizes[0] / CC;  // number of active sites

    int*   idx_map = (int*)d_ws;
    float* w_t     = (float*)((char*)d_ws + (size_t)BB * HH * WW * sizeof(int));

    // 1) idx_map = -1
    hipMemsetAsync(idx_map, 0xFF, (size_t)BB * HH * WW * sizeof(int), stream);
    // 2) scatter site ids
    smconv_scatter<<<(n + 255) / 256, 256, 0, stream>>>(idx, idx_map, n);
    // 3) transpose weights to (tap, C)
    smconv_wt<<<(KK * KK * CC + 255) / 256, 256, 0, stream>>>(w, w_t);
    // 4) region conv: one block per 64x32 region, 512 blocks = 2/CU
    smconv_conv_region<<<NREG, NT, 0, stream>>>(feat, w_t, bias, idx_map, out);
}